// Round 7
// baseline (522.678 us; speedup 1.0000x reference)
//
#include <hip/hip_runtime.h>
#include <stdint.h>

typedef __attribute__((ext_vector_type(8))) short short8;
typedef __attribute__((ext_vector_type(4))) float f32x4;

__device__ __forceinline__ unsigned short f2b(float f) {
  union { float f; uint32_t u; } v; v.f = f;
  uint32_t r = (v.u + 0x7fffu + ((v.u >> 16) & 1u)) >> 16;
  return (unsigned short)r;
}
__device__ __forceinline__ float b2f(unsigned short h) {
  union { uint32_t u; float f; } v; v.u = ((uint32_t)h) << 16; return v.f;
}

__device__ __forceinline__ void load_lds16(const void* g, void* l) {
  __builtin_amdgcn_global_load_lds(
      (const __attribute__((address_space(1))) uint32_t*)g,
      (__attribute__((address_space(3))) uint32_t*)l, 16, 0, 0);
}

// ------------- 5x fused 256x256 transpose+cast (f32 W[k][n] -> bf16 WT[n][k]) -------------
__global__ void transpose_cast5(
    const float* __restrict__ W0, const float* __restrict__ W1,
    const float* __restrict__ W2, const float* __restrict__ W3,
    const float* __restrict__ W4,
    unsigned short* __restrict__ T0, unsigned short* __restrict__ T1,
    unsigned short* __restrict__ T2, unsigned short* __restrict__ T3,
    unsigned short* __restrict__ T4) {
  const float* W; unsigned short* T;
  switch (blockIdx.y) {
    case 0: W = W0; T = T0; break;
    case 1: W = W1; T = T1; break;
    case 2: W = W2; T = T2; break;
    case 3: W = W3; T = T3; break;
    default: W = W4; T = T4; break;
  }
  __shared__ unsigned short t[32][33];
  int bx = blockIdx.x & 7, by = blockIdx.x >> 3;
  int x = threadIdx.x & 31, y = threadIdx.x >> 5;  // 32x8
  for (int i = 0; i < 32; i += 8)
    t[y + i][x] = f2b(W[(by * 32 + y + i) * 256 + bx * 32 + x]);
  __syncthreads();
  for (int i = 0; i < 32; i += 8)
    T[(bx * 32 + y + i) * 256 + by * 32 + x] = t[x][y + i];
}

// ------------- stripe-resident GEMM: A staged ONCE, NMAT x 4 B-panels -------------
// Block = 64 A-rows, full K=256 resident in LDS (32 KB bf16, swizzled).
// Pass loop: {mat 0..NMAT-1} x {colblk 0..3}: stage B panel (64 cols x 256 k,
// 32 KB, global_load_lds w/ pre-swizzled source), 8 K-steps of 16x16x32 MFMA.
// Wave w owns rows [w*16, w*16+16); acc[4] f32x4 per pass.
// mat 0 -> f32 out0; mats 1,2 -> bf16 out1/out2.
template <int NMAT>
__global__ __launch_bounds__(256, 2) void gemm_stripe(
    const float* __restrict__ A,
    const unsigned short* __restrict__ WT0, const unsigned short* __restrict__ WT1,
    const unsigned short* __restrict__ WT2,
    const float* __restrict__ b0, const float* __restrict__ b1,
    const float* __restrict__ b2,
    float* __restrict__ out0, unsigned short* __restrict__ out1,
    unsigned short* __restrict__ out2, int M) {
  __shared__ uint8_t lds[65536];
  uint8_t* ldsA = lds;            // [64 rows][32 chunks of 16B], chunk^=(row&7)
  uint8_t* ldsB = lds + 32768;    // [64 cols][32 chunks of 16B], chunk^=(col&7)

  const int tid = threadIdx.x;
  const int lane = tid & 63;
  const int w = tid >> 6;
  const int row0 = blockIdx.x * 64;

  // ---- Phase 1: stage A stripe (64 rows x 256 k), f32 -> bf16, swizzled ----
#pragma unroll
  for (int c = 0; c < 8; ++c) {
    int q = c * 256 + tid;          // chunk 0..2047
    int row = q >> 5, ch = q & 31;
    int ar = row0 + row;
    if (ar >= M) ar = M - 1;
    const float* ap = A + (size_t)ar * 256 + ch * 8;
    float4 f0 = *(const float4*)(ap);
    float4 f1 = *(const float4*)(ap + 4);
    short8 s;
    s[0] = (short)f2b(f0.x); s[1] = (short)f2b(f0.y);
    s[2] = (short)f2b(f0.z); s[3] = (short)f2b(f0.w);
    s[4] = (short)f2b(f1.x); s[5] = (short)f2b(f1.y);
    s[6] = (short)f2b(f1.z); s[7] = (short)f2b(f1.w);
    *(short8*)(ldsA + row * 512 + ((ch ^ (row & 7)) << 4)) = s;
  }

  // ---- Phase 2: passes over mats x column blocks ----
#pragma unroll
  for (int mat = 0; mat < NMAT; ++mat) {
    const unsigned short* WT = mat == 0 ? WT0 : (mat == 1 ? WT1 : WT2);
    const float* bb = mat == 0 ? b0 : (mat == 1 ? b1 : b2);
#pragma unroll
    for (int cb = 0; cb < 4; ++cb) {
      const int n0 = cb * 64;
      // stage B panel: 64 cols x 256 k (2048 chunks), source pre-swizzled
#pragma unroll
      for (int c = 0; c < 8; ++c) {
        int q = c * 256 + tid;
        int col = q >> 5, ch = q & 31;
        int lch = ch ^ (col & 7);
        load_lds16(WT + (size_t)(n0 + col) * 256 + lch * 8, ldsB + q * 16);
      }
      asm volatile("s_waitcnt vmcnt(0)" ::: "memory");
      __syncthreads();

      f32x4 acc[4] = {};
#pragma unroll
      for (int ks = 0; ks < 8; ++ks) {
        int c = ks * 4 + (lane >> 4);
        int arow = w * 16 + (lane & 15);
        short8 av = *(const short8*)(ldsA + arow * 512 + ((c ^ (arow & 7)) << 4));
#pragma unroll
        for (int n = 0; n < 4; ++n) {
          int col = n * 16 + (lane & 15);
          short8 bv = *(const short8*)(ldsB + col * 512 + ((c ^ (col & 7)) << 4));
          acc[n] = __builtin_amdgcn_mfma_f32_16x16x32_bf16(av, bv, acc[n], 0, 0, 0);
        }
      }

      // epilogue: + bias, store 16 rows x 64 cols per wave
#pragma unroll
      for (int n = 0; n < 4; ++n) {
        int col = n0 + n * 16 + (lane & 15);
        float bval = bb[col];
#pragma unroll
        for (int j = 0; j < 4; ++j) {
          int row = row0 + w * 16 + (lane >> 4) * 4 + j;
          if (row < M) {
            float v = acc[n][j] + bval;
            if (mat == 0)
              out0[(size_t)row * 256 + col] = v;
            else if (mat == 1)
              out1[(size_t)row * 256 + col] = f2b(v);
            else
              out2[(size_t)row * 256 + col] = f2b(v);
          }
        }
      }
      __syncthreads();  // protect ldsB before next stage
    }
  }
}

// ------------- CSR build (fused over 3 relations) -------------
__global__ void hist3(const int* __restrict__ d1, int E1, int* __restrict__ c1,
                      const int* __restrict__ d2, int E2, int* __restrict__ c2,
                      const int* __restrict__ d3, int E3, int* __restrict__ c3) {
  int i = blockIdx.x * blockDim.x + threadIdx.x;
  int stride = gridDim.x * blockDim.x;
  int tot = E1 + E2 + E3;
  for (; i < tot; i += stride) {
    if (i < E1) atomicAdd(&c1[d1[i]], 1);
    else if (i < E1 + E2) atomicAdd(&c2[d2[i - E1]], 1);
    else atomicAdd(&c3[d3[i - E1 - E2]], 1);
  }
}

__global__ void scan512_3(const int* __restrict__ c1, int* __restrict__ o1, int ns1,
                          const int* __restrict__ c2, int* __restrict__ o2, int ns2,
                          const int* __restrict__ c3, int* __restrict__ o3, int ns3,
                          int* __restrict__ bsum) {
  const int* in; int* out; int ns;
  switch (blockIdx.y) {
    case 0: in = c1; out = o1; ns = ns1; break;
    case 1: in = c2; out = o2; ns = ns2; break;
    default: in = c3; out = o3; ns = ns3; break;
  }
  if ((int)blockIdx.x * 512 >= ns) return;
  __shared__ int s[512];
  int t = threadIdx.x;
  int i = blockIdx.x * 512 + t;
  int v = (i < ns) ? in[i] : 0;
  s[t] = v;
  __syncthreads();
  for (int off = 1; off < 512; off <<= 1) {
    int x = s[t];
    int y = (t >= off) ? s[t - off] : 0;
    __syncthreads();
    s[t] = x + y;
    __syncthreads();
  }
  if (i < ns) out[i] = s[t] - v;  // exclusive
  if (t == 511) bsum[blockIdx.y * 512 + blockIdx.x] = s[511];
}

__global__ void scan_bsums3(int* __restrict__ bsum, int B1, int B2, int B3) {
  int rel = blockIdx.x;
  int B = rel == 0 ? B1 : (rel == 1 ? B2 : B3);
  int* bs = bsum + rel * 512;
  __shared__ int s[512];
  int t = threadIdx.x;
  int v = (t < B) ? bs[t] : 0;
  s[t] = v;
  __syncthreads();
  for (int off = 1; off < 512; off <<= 1) {
    int x = s[t];
    int y = (t >= off) ? s[t - off] : 0;
    __syncthreads();
    s[t] = x + y;
    __syncthreads();
  }
  if (t < B) bs[t] = s[t] - v;  // exclusive
}

__global__ void addoff3(int* __restrict__ o1, int* __restrict__ p1, int ns1,
                        int* __restrict__ o2, int* __restrict__ p2, int ns2,
                        int* __restrict__ o3, int* __restrict__ p3, int ns3,
                        const int* __restrict__ bsum) {
  int* o; int* p; int ns;
  switch (blockIdx.y) {
    case 0: o = o1; p = p1; ns = ns1; break;
    case 1: o = o2; p = p2; ns = ns2; break;
    default: o = o3; p = p3; ns = ns3; break;
  }
  int i = blockIdx.x * 512 + threadIdx.x;
  if (i < ns) {
    int v = o[i] + bsum[blockIdx.y * 512 + blockIdx.x];
    o[i] = v;
    p[i] = v;
  }
}

__global__ void bucket3(
    const int* __restrict__ d1, const int* __restrict__ s1in,
    const float* __restrict__ w1in, int E1, int* __restrict__ p1,
    int* __restrict__ s1, float* __restrict__ w1,
    const int* __restrict__ d2, const int* __restrict__ s2in, int E2,
    int* __restrict__ p2, int* __restrict__ s2,
    const int* __restrict__ d3, const int* __restrict__ s3in, int E3,
    int* __restrict__ p3, int* __restrict__ s3) {
  int i = blockIdx.x * blockDim.x + threadIdx.x;
  int stride = gridDim.x * blockDim.x;
  int tot = E1 + E2 + E3;
  for (; i < tot; i += stride) {
    if (i < E1) {
      int p = atomicAdd(&p1[d1[i]], 1);
      s1[p] = s1in[i];
      w1[p] = w1in[i];
    } else if (i < E1 + E2) {
      int k = i - E1;
      int p = atomicAdd(&p2[d2[k]], 1);
      s2[p] = s2in[k];
    } else {
      int k = i - E1 - E2;
      int p = atomicAdd(&p3[d3[k]], 1);
      s3[p] = s3in[k];
    }
  }
}

// ------------- fused gather-accumulate + ELU (2 waves per dst row) -------------
template <bool WEIGHTED>
__device__ __forceinline__ void gather_acc(float& v0, float& v1,
                                           const unsigned short* __restrict__ msg,
                                           const int* __restrict__ srcs,
                                           const float* __restrict__ wgts,
                                           int b, int e, int chan) {
  int j = b;
  for (; j + 4 <= e; j += 4) {
    int sa = srcs[j], sb = srcs[j + 1], sc = srcs[j + 2], sd = srcs[j + 3];
    float wa = 1.f, wb = 1.f, wc = 1.f, wd = 1.f;
    if (WEIGHTED) { wa = wgts[j]; wb = wgts[j + 1]; wc = wgts[j + 2]; wd = wgts[j + 3]; }
    ushort2 ma = *(const ushort2*)(msg + ((size_t)sa << 8) + chan);
    ushort2 mb = *(const ushort2*)(msg + ((size_t)sb << 8) + chan);
    ushort2 mc = *(const ushort2*)(msg + ((size_t)sc << 8) + chan);
    ushort2 md = *(const ushort2*)(msg + ((size_t)sd << 8) + chan);
    v0 += wa * b2f(ma.x) + wb * b2f(mb.x) + wc * b2f(mc.x) + wd * b2f(md.x);
    v1 += wa * b2f(ma.y) + wb * b2f(mb.y) + wc * b2f(mc.y) + wd * b2f(md.y);
  }
  if (j + 2 <= e) {
    int sa = srcs[j], sb = srcs[j + 1];
    float wa = 1.f, wb = 1.f;
    if (WEIGHTED) { wa = wgts[j]; wb = wgts[j + 1]; }
    ushort2 ma = *(const ushort2*)(msg + ((size_t)sa << 8) + chan);
    ushort2 mb = *(const ushort2*)(msg + ((size_t)sb << 8) + chan);
    v0 += wa * b2f(ma.x) + wb * b2f(mb.x);
    v1 += wa * b2f(ma.y) + wb * b2f(mb.y);
    j += 2;
  }
  if (j < e) {
    int s = srcs[j];
    float w = WEIGHTED ? wgts[j] : 1.f;
    ushort2 m = *(const ushort2*)(msg + ((size_t)s << 8) + chan);
    v0 += w * b2f(m.x);
    v1 += w * b2f(m.y);
  }
}

__global__ void accum_fused(
    float* __restrict__ io_p, int Np, float* __restrict__ io_a, int Na,
    const unsigned short* __restrict__ msg1, const int* __restrict__ off1,
    const int* __restrict__ s1, const float* __restrict__ w1,
    const unsigned short* __restrict__ msg2, const int* __restrict__ off2,
    const int* __restrict__ s2,
    const unsigned short* __restrict__ msg3, const int* __restrict__ off3,
    const int* __restrict__ s3) {
  int gw = (blockIdx.x * blockDim.x + threadIdx.x) >> 6;
  int lane = threadIdx.x & 63;
  int row = gw >> 1;
  int chan = (gw & 1) * 128 + lane * 2;
  float* rp;
  float v0, v1;
  if (row < Np) {
    rp = io_p + (size_t)row * 256 + chan;
    float2 v = *(float2*)rp;
    v0 = v.x; v1 = v.y;
    gather_acc<true>(v0, v1, msg1, s1, w1, off1[row], off1[row + 1], chan);
    gather_acc<false>(v0, v1, msg2, s2, nullptr, off2[row], off2[row + 1], chan);
  } else if (row < Np + Na) {
    int r = row - Np;
    rp = io_a + (size_t)r * 256 + chan;
    float2 v = *(float2*)rp;
    v0 = v.x; v1 = v.y;
    gather_acc<false>(v0, v1, msg3, s3, nullptr, off3[r], off3[r + 1], chan);
  } else {
    return;
  }
  float2 o;
  o.x = v0 > 0.f ? v0 : expf(v0) - 1.f;
  o.y = v1 > 0.f ? v1 : expf(v1) - 1.f;
  *(float2*)rp = o;
}

extern "C" void kernel_launch(void* const* d_in, const int* in_sizes, int n_in,
                              void* d_out, int out_size, void* d_ws, size_t ws_size,
                              hipStream_t stream) {
  const float* x_p = (const float*)d_in[0];
  const float* x_a = (const float*)d_in[1];
  const int* c_src = (const int*)d_in[2];
  const int* c_dst = (const int*)d_in[3];
  const float* c_w = (const float*)d_in[4];
  const int* w_src = (const int*)d_in[5];
  const int* w_dst = (const int*)d_in[6];
  const int* wr_src = (const int*)d_in[7];
  const int* wr_dst = (const int*)d_in[8];
  const float* W_sp = (const float*)d_in[9];
  const float* b_sp = (const float*)d_in[10];
  const float* W_sa = (const float*)d_in[11];
  const float* b_sa = (const float*)d_in[12];
  const float* W_c  = (const float*)d_in[13];
  const float* b_c  = (const float*)d_in[14];
  const float* W_w  = (const float*)d_in[15];
  const float* b_w  = (const float*)d_in[16];
  const float* W_wr = (const float*)d_in[17];
  const float* b_wr = (const float*)d_in[18];

  const int Mp = in_sizes[0] / 256;
  const int Ma = in_sizes[1] / 256;
  const int Ec = in_sizes[2], Ew = in_sizes[5], Ewr = in_sizes[7];

  // ---- workspace bump allocator (256B aligned) ----
  size_t wo = 0;
  auto alloc = [&](size_t bytes) -> void* {
    void* p = (char*)d_ws + wo;
    wo += (bytes + 255) & ~(size_t)255;
    return p;
  };
  unsigned short* msg_c  = (unsigned short*)alloc((size_t)Mp * 512);
  unsigned short* msg_w  = (unsigned short*)alloc((size_t)Ma * 512);
  unsigned short* msg_wr = (unsigned short*)alloc((size_t)Mp * 512);
  unsigned short* WT_sp = (unsigned short*)alloc(131072);
  unsigned short* WT_sa = (unsigned short*)alloc(131072);
  unsigned short* WT_c  = (unsigned short*)alloc(131072);
  unsigned short* WT_w  = (unsigned short*)alloc(131072);
  unsigned short* WT_wr = (unsigned short*)alloc(131072);
  int* cnt_c  = (int*)alloc((size_t)((Mp + 1) + (Mp + 1) + (Ma + 1)) * 4);
  int* cnt_w  = cnt_c + (Mp + 1);
  int* cnt_wr = cnt_w + (Mp + 1);
  size_t cnt_bytes = (size_t)((Mp + 1) + (Mp + 1) + (Ma + 1)) * 4;
  int* off_c  = (int*)alloc((size_t)(Mp + 1) * 4);
  int* pos_c  = (int*)alloc((size_t)(Mp + 1) * 4);
  int* off_w  = (int*)alloc((size_t)(Mp + 1) * 4);
  int* pos_w  = (int*)alloc((size_t)(Mp + 1) * 4);
  int* off_wr = (int*)alloc((size_t)(Ma + 1) * 4);
  int* pos_wr = (int*)alloc((size_t)(Ma + 1) * 4);
  int* srcs_c  = (int*)alloc((size_t)Ec * 4);
  float* wgts_c = (float*)alloc((size_t)Ec * 4);
  int* srcs_w  = (int*)alloc((size_t)Ew * 4);
  int* srcs_wr = (int*)alloc((size_t)Ewr * 4);
  int* bsum = (int*)alloc(3 * 512 * 4);

  float* out_p = (float*)d_out;
  float* out_a = (float*)d_out + (size_t)Mp * 256;

  // ---- weight transposes (1 dispatch) ----
  {
    dim3 g(64, 5);
    transpose_cast5<<<g, 256, 0, stream>>>(W_sp, W_sa, W_c, W_w, W_wr,
                                           WT_sp, WT_sa, WT_c, WT_w, WT_wr);
  }

  // ---- CSR build (6 dispatches) ----
  const int ns1 = Mp + 1, ns2 = Mp + 1, ns3 = Ma + 1;
  const int B1 = (ns1 + 511) / 512, B2 = (ns2 + 511) / 512, B3 = (ns3 + 511) / 512;
  const int Bmax = B1 > B2 ? (B1 > B3 ? B1 : B3) : (B2 > B3 ? B2 : B3);
  hipMemsetAsync(cnt_c, 0, cnt_bytes, stream);
  hist3<<<256, 256, 0, stream>>>(c_dst, Ec, cnt_c, w_dst, Ew, cnt_w, wr_dst, Ewr, cnt_wr);
  {
    dim3 g(Bmax, 3);
    scan512_3<<<g, 512, 0, stream>>>(cnt_c, off_c, ns1, cnt_w, off_w, ns2,
                                     cnt_wr, off_wr, ns3, bsum);
    scan_bsums3<<<3, 512, 0, stream>>>(bsum, B1, B2, B3);
    addoff3<<<g, 512, 0, stream>>>(off_c, pos_c, ns1, off_w, pos_w, ns2,
                                   off_wr, pos_wr, ns3, bsum);
  }
  bucket3<<<256, 256, 0, stream>>>(c_dst, c_src, c_w, Ec, pos_c, srcs_c, wgts_c,
                                   w_dst, w_src, Ew, pos_w, srcs_w,
                                   wr_dst, wr_src, Ewr, pos_wr, srcs_wr);

  // ---- stripe-resident fused GEMMs ----
  gemm_stripe<3><<<(Mp + 63) / 64, 256, 0, stream>>>(
      x_p, WT_sp, WT_c, WT_wr, b_sp, b_c, b_wr, out_p, msg_c, msg_wr, Mp);
  gemm_stripe<2><<<(Ma + 63) / 64, 256, 0, stream>>>(
      x_a, WT_sa, WT_w, nullptr, b_sa, b_w, nullptr, out_a, msg_w, nullptr, Ma);

  // ---- fused gather-accumulate + ELU (2 waves per row) ----
  int totalWaves = 2 * (Mp + Ma);
  accum_fused<<<(totalWaves + 3) / 4, 256, 0, stream>>>(
      out_p, Mp, out_a, Ma,
      msg_c, off_c, srcs_c, wgts_c,
      msg_w, off_w, srcs_w,
      msg_wr, off_wr, srcs_wr);
}

// Round 8
// 462.132 us; speedup vs baseline: 1.1310x; 1.1310x over previous
//
#include <hip/hip_runtime.h>
#include <stdint.h>

typedef __attribute__((ext_vector_type(8))) short short8;
typedef __attribute__((ext_vector_type(4))) float f32x4;

__device__ __forceinline__ unsigned short f2b(float f) {
  union { float f; uint32_t u; } v; v.f = f;
  uint32_t r = (v.u + 0x7fffu + ((v.u >> 16) & 1u)) >> 16;
  return (unsigned short)r;
}
__device__ __forceinline__ float b2f(unsigned short h) {
  union { uint32_t u; float f; } v; v.u = ((uint32_t)h) << 16; return v.f;
}

__device__ __forceinline__ void load_lds16(const void* g, void* l) {
  __builtin_amdgcn_global_load_lds(
      (const __attribute__((address_space(1))) uint32_t*)g,
      (__attribute__((address_space(3))) uint32_t*)l, 16, 0, 0);
}

// ------------- f32 -> bf16 convert (for paper features) -------------
__global__ void cvt_bf16(const float4* __restrict__ in, ushort4* __restrict__ out,
                         int n4) {
  int i = blockIdx.x * blockDim.x + threadIdx.x;
  int stride = gridDim.x * blockDim.x;
  for (; i < n4; i += stride) {
    float4 f = in[i];
    ushort4 o;
    o.x = f2b(f.x); o.y = f2b(f.y); o.z = f2b(f.z); o.w = f2b(f.w);
    out[i] = o;
  }
}

// ------------- 5x fused 256x256 transpose+cast (f32 W[k][n] -> bf16 WT[n][k]) -------------
__global__ void transpose_cast5(
    const float* __restrict__ W0, const float* __restrict__ W1,
    const float* __restrict__ W2, const float* __restrict__ W3,
    const float* __restrict__ W4,
    unsigned short* __restrict__ T0, unsigned short* __restrict__ T1,
    unsigned short* __restrict__ T2, unsigned short* __restrict__ T3,
    unsigned short* __restrict__ T4) {
  const float* W; unsigned short* T;
  switch (blockIdx.y) {
    case 0: W = W0; T = T0; break;
    case 1: W = W1; T = T1; break;
    case 2: W = W2; T = T2; break;
    case 3: W = W3; T = T3; break;
    default: W = W4; T = T4; break;
  }
  __shared__ unsigned short t[32][33];
  int bx = blockIdx.x & 7, by = blockIdx.x >> 3;
  int x = threadIdx.x & 31, y = threadIdx.x >> 5;  // 32x8
  for (int i = 0; i < 32; i += 8)
    t[y + i][x] = f2b(W[(by * 32 + y + i) * 256 + bx * 32 + x]);
  __syncthreads();
  for (int i = 0; i < 32; i += 8)
    T[(bx * 32 + y + i) * 256 + by * 32 + x] = t[x][y + i];
}

// ------------- multi-B GEMM (round-6 structure + XCD swizzle + bf16-A path) -------------
// Block tile 128 rows x 64 cols, BK=64, 4 waves (2x2), wave tile 64x32.
// 1-D grid of nstripes*4; bijective XCD swizzle puts the 4 col-blocks of a
// stripe on the same XCD so the A tile rides that XCD's L2.
// BF16A: A already bf16 -> global_load_lds (pre-swizzled source).
// else : A f32 -> reg stage -> cvt -> swizzled ds_write.
template <int NMAT, bool BF16A>
__global__ __launch_bounds__(256, 3) void gemm_multi(
    const void* __restrict__ Aptr,
    const unsigned short* __restrict__ WT0, const unsigned short* __restrict__ WT1,
    const unsigned short* __restrict__ WT2,
    const float* __restrict__ b0, const float* __restrict__ b1,
    const float* __restrict__ b2,
    float* __restrict__ out0, unsigned short* __restrict__ out1,
    unsigned short* __restrict__ out2, int M, int nstripes) {
  __shared__ uint8_t lds[16384 + NMAT * 8192];
  uint8_t* ldsA = lds;

  // bijective XCD swizzle (m204): orig%8 = xcd, contiguous wgid chunk per XCD
  const int nwg = nstripes * 4;
  const int orig = blockIdx.x;
  const int q = nwg >> 3, r = nwg & 7;
  const int xcd = orig & 7, idx = orig >> 3;
  const int wgid = (xcd < r ? xcd * (q + 1) : r * (q + 1) + (xcd - r) * q) + idx;
  const int row0 = (wgid >> 2) * 128;
  const int n0 = (wgid & 3) * 64;

  const int tid = threadIdx.x;
  const int lane = tid & 63;
  const int w = tid >> 6;
  const int wr = w >> 1, wc = w & 1;

  const unsigned short* Ab = (const unsigned short*)Aptr;
  const float* Af = (const float*)Aptr;

  f32x4 acc[NMAT][4][2] = {};

  for (int kt = 0; kt < 4; ++kt) {
    const int kk = kt << 6;
    // --- stage B tiles (64 cols x 64 k each) via global_load_lds ---
#pragma unroll
    for (int mat = 0; mat < NMAT; ++mat) {
      const unsigned short* WT = mat == 0 ? WT0 : (mat == 1 ? WT1 : WT2);
      uint8_t* ldsB = lds + 16384 + mat * 8192;
#pragma unroll
      for (int c = 0; c < 2; ++c) {
        int qq = c * 256 + tid;           // 16B chunk index, 512 chunks
        int row = qq >> 3, ch = qq & 7;
        int lch = ch ^ (row & 7);
        load_lds16(WT + (size_t)(n0 + row) * 256 + kk + lch * 8, ldsB + qq * 16);
      }
    }
    // --- stage A (128 rows x 64 k) ---
    if constexpr (BF16A) {
#pragma unroll
      for (int c = 0; c < 4; ++c) {
        int qq = c * 256 + tid;           // 1024 chunks
        int row = qq >> 3, ch = qq & 7;
        int lch = ch ^ (row & 7);
        int ar = row0 + row;
        if (ar >= M) ar = M - 1;
        load_lds16(Ab + (size_t)ar * 256 + kk + lch * 8, ldsA + qq * 16);
      }
    } else {
#pragma unroll
      for (int c = 0; c < 4; ++c) {
        int qq = c * 256 + tid;
        int row = qq >> 3, ch = qq & 7;
        int ar = row0 + row;
        if (ar >= M) ar = M - 1;
        const float* ap = Af + (size_t)ar * 256 + kk + ch * 8;
        float4 f0 = *(const float4*)(ap);
        float4 f1 = *(const float4*)(ap + 4);
        short8 s;
        s[0] = (short)f2b(f0.x); s[1] = (short)f2b(f0.y);
        s[2] = (short)f2b(f0.z); s[3] = (short)f2b(f0.w);
        s[4] = (short)f2b(f1.x); s[5] = (short)f2b(f1.y);
        s[6] = (short)f2b(f1.z); s[7] = (short)f2b(f1.w);
        *(short8*)(ldsA + row * 128 + ((ch ^ (row & 7)) << 4)) = s;
      }
    }
    asm volatile("s_waitcnt vmcnt(0)" ::: "memory");
    __syncthreads();

#pragma unroll
    for (int s = 0; s < 2; ++s) {
      const int cbase = (s << 2) + (lane >> 4);
      short8 av[4];
#pragma unroll
      for (int m = 0; m < 4; ++m) {
        int rrow = wr * 64 + m * 16 + (lane & 15);
        av[m] = *(const short8*)(ldsA + rrow * 128 + ((cbase ^ (rrow & 7)) << 4));
      }
#pragma unroll
      for (int mat = 0; mat < NMAT; ++mat) {
        uint8_t* ldsB = lds + 16384 + mat * 8192;
        short8 bv[2];
#pragma unroll
        for (int n = 0; n < 2; ++n) {
          int cc = wc * 32 + n * 16 + (lane & 15);
          bv[n] = *(const short8*)(ldsB + cc * 128 + ((cbase ^ (cc & 7)) << 4));
        }
#pragma unroll
        for (int m = 0; m < 4; ++m)
#pragma unroll
          for (int n = 0; n < 2; ++n)
            acc[mat][m][n] = __builtin_amdgcn_mfma_f32_16x16x32_bf16(
                av[m], bv[n], acc[mat][m][n], 0, 0, 0);
      }
    }
    __syncthreads();
  }

  // epilogue
#pragma unroll
  for (int mat = 0; mat < NMAT; ++mat) {
    const float* bb = mat == 0 ? b0 : (mat == 1 ? b1 : b2);
#pragma unroll
    for (int n = 0; n < 2; ++n) {
      int col = n0 + wc * 32 + n * 16 + (lane & 15);
      float bval = bb[col];
#pragma unroll
      for (int m = 0; m < 4; ++m) {
#pragma unroll
        for (int j = 0; j < 4; ++j) {
          int row = row0 + wr * 64 + m * 16 + (lane >> 4) * 4 + j;
          if (row < M) {
            float v = acc[mat][m][n][j] + bval;
            if (mat == 0)
              out0[(size_t)row * 256 + col] = v;
            else if (mat == 1)
              out1[(size_t)row * 256 + col] = f2b(v);
            else
              out2[(size_t)row * 256 + col] = f2b(v);
          }
        }
      }
    }
  }
}

// ------------- CSR build (fused over 3 relations) -------------
__global__ void hist3(const int* __restrict__ d1, int E1, int* __restrict__ c1,
                      const int* __restrict__ d2, int E2, int* __restrict__ c2,
                      const int* __restrict__ d3, int E3, int* __restrict__ c3) {
  int i = blockIdx.x * blockDim.x + threadIdx.x;
  int stride = gridDim.x * blockDim.x;
  int tot = E1 + E2 + E3;
  for (; i < tot; i += stride) {
    if (i < E1) atomicAdd(&c1[d1[i]], 1);
    else if (i < E1 + E2) atomicAdd(&c2[d2[i - E1]], 1);
    else atomicAdd(&c3[d3[i - E1 - E2]], 1);
  }
}

__global__ void scan512_3(const int* __restrict__ c1, int* __restrict__ o1, int ns1,
                          const int* __restrict__ c2, int* __restrict__ o2, int ns2,
                          const int* __restrict__ c3, int* __restrict__ o3, int ns3,
                          int* __restrict__ bsum) {
  const int* in; int* out; int ns;
  switch (blockIdx.y) {
    case 0: in = c1; out = o1; ns = ns1; break;
    case 1: in = c2; out = o2; ns = ns2; break;
    default: in = c3; out = o3; ns = ns3; break;
  }
  if ((int)blockIdx.x * 512 >= ns) return;
  __shared__ int s[512];
  int t = threadIdx.x;
  int i = blockIdx.x * 512 + t;
  int v = (i < ns) ? in[i] : 0;
  s[t] = v;
  __syncthreads();
  for (int off = 1; off < 512; off <<= 1) {
    int x = s[t];
    int y = (t >= off) ? s[t - off] : 0;
    __syncthreads();
    s[t] = x + y;
    __syncthreads();
  }
  if (i < ns) out[i] = s[t] - v;  // exclusive
  if (t == 511) bsum[blockIdx.y * 512 + blockIdx.x] = s[511];
}

__global__ void scan_bsums3(int* __restrict__ bsum, int B1, int B2, int B3) {
  int rel = blockIdx.x;
  int B = rel == 0 ? B1 : (rel == 1 ? B2 : B3);
  int* bs = bsum + rel * 512;
  __shared__ int s[512];
  int t = threadIdx.x;
  int v = (t < B) ? bs[t] : 0;
  s[t] = v;
  __syncthreads();
  for (int off = 1; off < 512; off <<= 1) {
    int x = s[t];
    int y = (t >= off) ? s[t - off] : 0;
    __syncthreads();
    s[t] = x + y;
    __syncthreads();
  }
  if (t < B) bs[t] = s[t] - v;  // exclusive
}

__global__ void addoff3(int* __restrict__ o1, int* __restrict__ p1, int ns1,
                        int* __restrict__ o2, int* __restrict__ p2, int ns2,
                        int* __restrict__ o3, int* __restrict__ p3, int ns3,
                        const int* __restrict__ bsum) {
  int* o; int* p; int ns;
  switch (blockIdx.y) {
    case 0: o = o1; p = p1; ns = ns1; break;
    case 1: o = o2; p = p2; ns = ns2; break;
    default: o = o3; p = p3; ns = ns3; break;
  }
  int i = blockIdx.x * 512 + threadIdx.x;
  if (i < ns) {
    int v = o[i] + bsum[blockIdx.y * 512 + blockIdx.x];
    o[i] = v;
    p[i] = v;
  }
}

__global__ void bucket3(
    const int* __restrict__ d1, const int* __restrict__ s1in,
    const float* __restrict__ w1in, int E1, int* __restrict__ p1,
    int* __restrict__ s1, float* __restrict__ w1,
    const int* __restrict__ d2, const int* __restrict__ s2in, int E2,
    int* __restrict__ p2, int* __restrict__ s2,
    const int* __restrict__ d3, const int* __restrict__ s3in, int E3,
    int* __restrict__ p3, int* __restrict__ s3) {
  int i = blockIdx.x * blockDim.x + threadIdx.x;
  int stride = gridDim.x * blockDim.x;
  int tot = E1 + E2 + E3;
  for (; i < tot; i += stride) {
    if (i < E1) {
      int p = atomicAdd(&p1[d1[i]], 1);
      s1[p] = s1in[i];
      w1[p] = w1in[i];
    } else if (i < E1 + E2) {
      int k = i - E1;
      int p = atomicAdd(&p2[d2[k]], 1);
      s2[p] = s2in[k];
    } else {
      int k = i - E1 - E2;
      int p = atomicAdd(&p3[d3[k]], 1);
      s3[p] = s3in[k];
    }
  }
}

// ------------- fused gather-accumulate + ELU (2 waves per dst row) -------------
template <bool WEIGHTED>
__device__ __forceinline__ void gather_acc(float& v0, float& v1,
                                           const unsigned short* __restrict__ msg,
                                           const int* __restrict__ srcs,
                                           const float* __restrict__ wgts,
                                           int b, int e, int chan) {
  int j = b;
  for (; j + 4 <= e; j += 4) {
    int sa = srcs[j], sb = srcs[j + 1], sc = srcs[j + 2], sd = srcs[j + 3];
    float wa = 1.f, wb = 1.f, wc = 1.f, wd = 1.f;
    if (WEIGHTED) { wa = wgts[j]; wb = wgts[j + 1]; wc = wgts[j + 2]; wd = wgts[j + 3]; }
    ushort2 ma = *(const ushort2*)(msg + ((size_t)sa << 8) + chan);
    ushort2 mb = *(const ushort2*)(msg + ((size_t)sb << 8) + chan);
    ushort2 mc = *(const ushort2*)(msg + ((size_t)sc << 8) + chan);
    ushort2 md = *(const ushort2*)(msg + ((size_t)sd << 8) + chan);
    v0 += wa * b2f(ma.x) + wb * b2f(mb.x) + wc * b2f(mc.x) + wd * b2f(md.x);
    v1 += wa * b2f(ma.y) + wb * b2f(mb.y) + wc * b2f(mc.y) + wd * b2f(md.y);
  }
  if (j + 2 <= e) {
    int sa = srcs[j], sb = srcs[j + 1];
    float wa = 1.f, wb = 1.f;
    if (WEIGHTED) { wa = wgts[j]; wb = wgts[j + 1]; }
    ushort2 ma = *(const ushort2*)(msg + ((size_t)sa << 8) + chan);
    ushort2 mb = *(const ushort2*)(msg + ((size_t)sb << 8) + chan);
    v0 += wa * b2f(ma.x) + wb * b2f(mb.x);
    v1 += wa * b2f(ma.y) + wb * b2f(mb.y);
    j += 2;
  }
  if (j < e) {
    int s = srcs[j];
    float w = WEIGHTED ? wgts[j] : 1.f;
    ushort2 m = *(const ushort2*)(msg + ((size_t)s << 8) + chan);
    v0 += w * b2f(m.x);
    v1 += w * b2f(m.y);
  }
}

__global__ void accum_fused(
    float* __restrict__ io_p, int Np, float* __restrict__ io_a, int Na,
    const unsigned short* __restrict__ msg1, const int* __restrict__ off1,
    const int* __restrict__ s1, const float* __restrict__ w1,
    const unsigned short* __restrict__ msg2, const int* __restrict__ off2,
    const int* __restrict__ s2,
    const unsigned short* __restrict__ msg3, const int* __restrict__ off3,
    const int* __restrict__ s3) {
  int gw = (blockIdx.x * blockDim.x + threadIdx.x) >> 6;
  int lane = threadIdx.x & 63;
  int row = gw >> 1;
  int chan = (gw & 1) * 128 + lane * 2;
  float* rp;
  float v0, v1;
  if (row < Np) {
    rp = io_p + (size_t)row * 256 + chan;
    float2 v = *(float2*)rp;
    v0 = v.x; v1 = v.y;
    gather_acc<true>(v0, v1, msg1, s1, w1, off1[row], off1[row + 1], chan);
    gather_acc<false>(v0, v1, msg2, s2, nullptr, off2[row], off2[row + 1], chan);
  } else if (row < Np + Na) {
    int r = row - Np;
    rp = io_a + (size_t)r * 256 + chan;
    float2 v = *(float2*)rp;
    v0 = v.x; v1 = v.y;
    gather_acc<false>(v0, v1, msg3, s3, nullptr, off3[r], off3[r + 1], chan);
  } else {
    return;
  }
  float2 o;
  o.x = v0 > 0.f ? v0 : expf(v0) - 1.f;
  o.y = v1 > 0.f ? v1 : expf(v1) - 1.f;
  *(float2*)rp = o;
}

extern "C" void kernel_launch(void* const* d_in, const int* in_sizes, int n_in,
                              void* d_out, int out_size, void* d_ws, size_t ws_size,
                              hipStream_t stream) {
  const float* x_p = (const float*)d_in[0];
  const float* x_a = (const float*)d_in[1];
  const int* c_src = (const int*)d_in[2];
  const int* c_dst = (const int*)d_in[3];
  const float* c_w = (const float*)d_in[4];
  const int* w_src = (const int*)d_in[5];
  const int* w_dst = (const int*)d_in[6];
  const int* wr_src = (const int*)d_in[7];
  const int* wr_dst = (const int*)d_in[8];
  const float* W_sp = (const float*)d_in[9];
  const float* b_sp = (const float*)d_in[10];
  const float* W_sa = (const float*)d_in[11];
  const float* b_sa = (const float*)d_in[12];
  const float* W_c  = (const float*)d_in[13];
  const float* b_c  = (const float*)d_in[14];
  const float* W_w  = (const float*)d_in[15];
  const float* b_w  = (const float*)d_in[16];
  const float* W_wr = (const float*)d_in[17];
  const float* b_wr = (const float*)d_in[18];

  const int Mp = in_sizes[0] / 256;
  const int Ma = in_sizes[1] / 256;
  const int Ec = in_sizes[2], Ew = in_sizes[5], Ewr = in_sizes[7];

  // ---- workspace bump allocator (256B aligned); total ~187 MB ----
  size_t wo = 0;
  auto alloc = [&](size_t bytes) -> void* {
    void* p = (char*)d_ws + wo;
    wo += (bytes + 255) & ~(size_t)255;
    return p;
  };
  unsigned short* msg_c  = (unsigned short*)alloc((size_t)Mp * 512);
  unsigned short* msg_w  = (unsigned short*)alloc((size_t)Ma * 512);
  unsigned short* msg_wr = (unsigned short*)alloc((size_t)Mp * 512);
  unsigned short* Axp    = (unsigned short*)alloc((size_t)Mp * 512);  // bf16 x_p
  unsigned short* WT_sp = (unsigned short*)alloc(131072);
  unsigned short* WT_sa = (unsigned short*)alloc(131072);
  unsigned short* WT_c  = (unsigned short*)alloc(131072);
  unsigned short* WT_w  = (unsigned short*)alloc(131072);
  unsigned short* WT_wr = (unsigned short*)alloc(131072);
  int* cnt_c  = (int*)alloc((size_t)((Mp + 1) + (Mp + 1) + (Ma + 1)) * 4);
  int* cnt_w  = cnt_c + (Mp + 1);
  int* cnt_wr = cnt_w + (Mp + 1);
  size_t cnt_bytes = (size_t)((Mp + 1) + (Mp + 1) + (Ma + 1)) * 4;
  int* off_c  = (int*)alloc((size_t)(Mp + 1) * 4);
  int* pos_c  = (int*)alloc((size_t)(Mp + 1) * 4);
  int* off_w  = (int*)alloc((size_t)(Mp + 1) * 4);
  int* pos_w  = (int*)alloc((size_t)(Mp + 1) * 4);
  int* off_wr = (int*)alloc((size_t)(Ma + 1) * 4);
  int* pos_wr = (int*)alloc((size_t)(Ma + 1) * 4);
  int* srcs_c  = (int*)alloc((size_t)Ec * 4);
  float* wgts_c = (float*)alloc((size_t)Ec * 4);
  int* srcs_w  = (int*)alloc((size_t)Ew * 4);
  int* srcs_wr = (int*)alloc((size_t)Ewr * 4);
  int* bsum = (int*)alloc(3 * 512 * 4);

  float* out_p = (float*)d_out;
  float* out_a = (float*)d_out + (size_t)Mp * 256;

  // ---- prep: x_p -> bf16, weight transposes ----
  cvt_bf16<<<2048, 256, 0, stream>>>((const float4*)x_p, (ushort4*)Axp, Mp * 64);
  {
    dim3 g(64, 5);
    transpose_cast5<<<g, 256, 0, stream>>>(W_sp, W_sa, W_c, W_w, W_wr,
                                           WT_sp, WT_sa, WT_c, WT_w, WT_wr);
  }

  // ---- CSR build (6 dispatches) ----
  const int ns1 = Mp + 1, ns2 = Mp + 1, ns3 = Ma + 1;
  const int B1 = (ns1 + 511) / 512, B2 = (ns2 + 511) / 512, B3 = (ns3 + 511) / 512;
  const int Bmax = B1 > B2 ? (B1 > B3 ? B1 : B3) : (B2 > B3 ? B2 : B3);
  hipMemsetAsync(cnt_c, 0, cnt_bytes, stream);
  hist3<<<256, 256, 0, stream>>>(c_dst, Ec, cnt_c, w_dst, Ew, cnt_w, wr_dst, Ewr, cnt_wr);
  {
    dim3 g(Bmax, 3);
    scan512_3<<<g, 512, 0, stream>>>(cnt_c, off_c, ns1, cnt_w, off_w, ns2,
                                     cnt_wr, off_wr, ns3, bsum);
    scan_bsums3<<<3, 512, 0, stream>>>(bsum, B1, B2, B3);
    addoff3<<<g, 512, 0, stream>>>(off_c, pos_c, ns1, off_w, pos_w, ns2,
                                   off_wr, pos_wr, ns3, bsum);
  }
  bucket3<<<256, 256, 0, stream>>>(c_dst, c_src, c_w, Ec, pos_c, srcs_c, wgts_c,
                                   w_dst, w_src, Ew, pos_w, srcs_w,
                                   wr_dst, wr_src, Ewr, pos_wr, srcs_wr);

  // ---- fused GEMMs (XCD-swizzled 1-D grids) ----
  const int nsp = (Mp + 127) / 128, nsa = (Ma + 127) / 128;
  gemm_multi<3, true><<<nsp * 4, 256, 0, stream>>>(
      Axp, WT_sp, WT_c, WT_wr, b_sp, b_c, b_wr, out_p, msg_c, msg_wr, Mp, nsp);
  gemm_multi<2, false><<<nsa * 4, 256, 0, stream>>>(
      x_a, WT_sa, WT_w, nullptr, b_sa, b_w, nullptr, out_a, msg_w, nullptr, Ma, nsa);

  // ---- fused gather-accumulate + ELU (2 waves per row) ----
  int totalWaves = 2 * (Mp + Ma);
  accum_fused<<<(totalWaves + 3) / 4, 256, 0, stream>>>(
      out_p, Mp, out_a, Ma,
      msg_c, off_c, srcs_c, wgts_c,
      msg_w, off_w, srcs_w,
      msg_wr, off_wr, srcs_wr);
}

// Round 9
// 412.373 us; speedup vs baseline: 1.2675x; 1.1207x over previous
//
#include <hip/hip_runtime.h>
#include <stdint.h>

typedef __attribute__((ext_vector_type(8))) short short8;
typedef __attribute__((ext_vector_type(4))) float f32x4;

__device__ __forceinline__ unsigned short f2b(float f) {
  union { float f; uint32_t u; } v; v.f = f;
  uint32_t r = (v.u + 0x7fffu + ((v.u >> 16) & 1u)) >> 16;
  return (unsigned short)r;
}
__device__ __forceinline__ float b2f(unsigned short h) {
  union { uint32_t u; float f; } v; v.u = ((uint32_t)h) << 16; return v.f;
}

__device__ __forceinline__ void load_lds16(const void* g, void* l) {
  __builtin_amdgcn_global_load_lds(
      (const __attribute__((address_space(1))) uint32_t*)g,
      (__attribute__((address_space(3))) uint32_t*)l, 16, 0, 0);
}

// ------------- f32 -> bf16 convert (for paper features) -------------
__global__ void cvt_bf16(const float4* __restrict__ in, ushort4* __restrict__ out,
                         int n4) {
  int i = blockIdx.x * blockDim.x + threadIdx.x;
  int stride = gridDim.x * blockDim.x;
  for (; i < n4; i += stride) {
    float4 f = in[i];
    ushort4 o;
    o.x = f2b(f.x); o.y = f2b(f.y); o.z = f2b(f.z); o.w = f2b(f.w);
    out[i] = o;
  }
}

// ------------- 5x fused 256x256 transpose+cast (f32 W[k][n] -> bf16 WT[n][k]) -------------
__global__ void transpose_cast5(
    const float* __restrict__ W0, const float* __restrict__ W1,
    const float* __restrict__ W2, const float* __restrict__ W3,
    const float* __restrict__ W4,
    unsigned short* __restrict__ T0, unsigned short* __restrict__ T1,
    unsigned short* __restrict__ T2, unsigned short* __restrict__ T3,
    unsigned short* __restrict__ T4) {
  const float* W; unsigned short* T;
  switch (blockIdx.y) {
    case 0: W = W0; T = T0; break;
    case 1: W = W1; T = T1; break;
    case 2: W = W2; T = T2; break;
    case 3: W = W3; T = T3; break;
    default: W = W4; T = T4; break;
  }
  __shared__ unsigned short t[32][33];
  int bx = blockIdx.x & 7, by = blockIdx.x >> 3;
  int x = threadIdx.x & 31, y = threadIdx.x >> 5;  // 32x8
  for (int i = 0; i < 32; i += 8)
    t[y + i][x] = f2b(W[(by * 32 + y + i) * 256 + bx * 32 + x]);
  __syncthreads();
  for (int i = 0; i < 32; i += 8)
    T[(bx * 32 + y + i) * 256 + by * 32 + x] = t[x][y + i];
}

// ------------- multi-B GEMM (128x64 tile, XCD swizzle, bf16-A path) -------------
template <int NMAT, bool BF16A>
__global__ __launch_bounds__(256, 3) void gemm_multi(
    const void* __restrict__ Aptr,
    const unsigned short* __restrict__ WT0, const unsigned short* __restrict__ WT1,
    const unsigned short* __restrict__ WT2,
    const float* __restrict__ b0, const float* __restrict__ b1,
    const float* __restrict__ b2,
    float* __restrict__ out0, unsigned short* __restrict__ out1,
    unsigned short* __restrict__ out2, int M, int nstripes) {
  __shared__ uint8_t lds[16384 + NMAT * 8192];
  uint8_t* ldsA = lds;

  // bijective XCD swizzle (m204)
  const int nwg = nstripes * 4;
  const int orig = blockIdx.x;
  const int q = nwg >> 3, r = nwg & 7;
  const int xcd = orig & 7, idx = orig >> 3;
  const int wgid = (xcd < r ? xcd * (q + 1) : r * (q + 1) + (xcd - r) * q) + idx;
  const int row0 = (wgid >> 2) * 128;
  const int n0 = (wgid & 3) * 64;

  const int tid = threadIdx.x;
  const int lane = tid & 63;
  const int w = tid >> 6;
  const int wr = w >> 1, wc = w & 1;

  const unsigned short* Ab = (const unsigned short*)Aptr;
  const float* Af = (const float*)Aptr;

  f32x4 acc[NMAT][4][2] = {};

  for (int kt = 0; kt < 4; ++kt) {
    const int kk = kt << 6;
#pragma unroll
    for (int mat = 0; mat < NMAT; ++mat) {
      const unsigned short* WT = mat == 0 ? WT0 : (mat == 1 ? WT1 : WT2);
      uint8_t* ldsB = lds + 16384 + mat * 8192;
#pragma unroll
      for (int c = 0; c < 2; ++c) {
        int qq = c * 256 + tid;
        int row = qq >> 3, ch = qq & 7;
        int lch = ch ^ (row & 7);
        load_lds16(WT + (size_t)(n0 + row) * 256 + kk + lch * 8, ldsB + qq * 16);
      }
    }
    if constexpr (BF16A) {
#pragma unroll
      for (int c = 0; c < 4; ++c) {
        int qq = c * 256 + tid;
        int row = qq >> 3, ch = qq & 7;
        int lch = ch ^ (row & 7);
        int ar = row0 + row;
        if (ar >= M) ar = M - 1;
        load_lds16(Ab + (size_t)ar * 256 + kk + lch * 8, ldsA + qq * 16);
      }
    } else {
#pragma unroll
      for (int c = 0; c < 4; ++c) {
        int qq = c * 256 + tid;
        int row = qq >> 3, ch = qq & 7;
        int ar = row0 + row;
        if (ar >= M) ar = M - 1;
        const float* ap = Af + (size_t)ar * 256 + kk + ch * 8;
        float4 f0 = *(const float4*)(ap);
        float4 f1 = *(const float4*)(ap + 4);
        short8 s;
        s[0] = (short)f2b(f0.x); s[1] = (short)f2b(f0.y);
        s[2] = (short)f2b(f0.z); s[3] = (short)f2b(f0.w);
        s[4] = (short)f2b(f1.x); s[5] = (short)f2b(f1.y);
        s[6] = (short)f2b(f1.z); s[7] = (short)f2b(f1.w);
        *(short8*)(ldsA + row * 128 + ((ch ^ (row & 7)) << 4)) = s;
      }
    }
    asm volatile("s_waitcnt vmcnt(0)" ::: "memory");
    __syncthreads();

#pragma unroll
    for (int s = 0; s < 2; ++s) {
      const int cbase = (s << 2) + (lane >> 4);
      short8 av[4];
#pragma unroll
      for (int m = 0; m < 4; ++m) {
        int rrow = wr * 64 + m * 16 + (lane & 15);
        av[m] = *(const short8*)(ldsA + rrow * 128 + ((cbase ^ (rrow & 7)) << 4));
      }
#pragma unroll
      for (int mat = 0; mat < NMAT; ++mat) {
        uint8_t* ldsB = lds + 16384 + mat * 8192;
        short8 bv[2];
#pragma unroll
        for (int n = 0; n < 2; ++n) {
          int cc = wc * 32 + n * 16 + (lane & 15);
          bv[n] = *(const short8*)(ldsB + cc * 128 + ((cbase ^ (cc & 7)) << 4));
        }
#pragma unroll
        for (int m = 0; m < 4; ++m)
#pragma unroll
          for (int n = 0; n < 2; ++n)
            acc[mat][m][n] = __builtin_amdgcn_mfma_f32_16x16x32_bf16(
                av[m], bv[n], acc[mat][m][n], 0, 0, 0);
      }
    }
    __syncthreads();
  }

#pragma unroll
  for (int mat = 0; mat < NMAT; ++mat) {
    const float* bb = mat == 0 ? b0 : (mat == 1 ? b1 : b2);
#pragma unroll
    for (int n = 0; n < 2; ++n) {
      int col = n0 + wc * 32 + n * 16 + (lane & 15);
      float bval = bb[col];
#pragma unroll
      for (int m = 0; m < 4; ++m) {
#pragma unroll
        for (int j = 0; j < 4; ++j) {
          int row = row0 + wr * 64 + m * 16 + (lane >> 4) * 4 + j;
          if (row < M) {
            float v = acc[mat][m][n][j] + bval;
            if (mat == 0)
              out0[(size_t)row * 256 + col] = v;
            else if (mat == 1)
              out1[(size_t)row * 256 + col] = f2b(v);
            else
              out2[(size_t)row * 256 + col] = f2b(v);
          }
        }
      }
    }
  }
}

// ------------- CSR build (fused over 3 relations) -------------
__global__ void hist3(const int* __restrict__ d1, int E1, int* __restrict__ c1,
                      const int* __restrict__ d2, int E2, int* __restrict__ c2,
                      const int* __restrict__ d3, int E3, int* __restrict__ c3) {
  int i = blockIdx.x * blockDim.x + threadIdx.x;
  int stride = gridDim.x * blockDim.x;
  int tot = E1 + E2 + E3;
  for (; i < tot; i += stride) {
    if (i < E1) atomicAdd(&c1[d1[i]], 1);
    else if (i < E1 + E2) atomicAdd(&c2[d2[i - E1]], 1);
    else atomicAdd(&c3[d3[i - E1 - E2]], 1);
  }
}

__global__ void scan512_3(const int* __restrict__ c1, int* __restrict__ o1, int ns1,
                          const int* __restrict__ c2, int* __restrict__ o2, int ns2,
                          const int* __restrict__ c3, int* __restrict__ o3, int ns3,
                          int* __restrict__ bsum) {
  const int* in; int* out; int ns;
  switch (blockIdx.y) {
    case 0: in = c1; out = o1; ns = ns1; break;
    case 1: in = c2; out = o2; ns = ns2; break;
    default: in = c3; out = o3; ns = ns3; break;
  }
  if ((int)blockIdx.x * 512 >= ns) return;
  __shared__ int s[512];
  int t = threadIdx.x;
  int i = blockIdx.x * 512 + t;
  int v = (i < ns) ? in[i] : 0;
  s[t] = v;
  __syncthreads();
  for (int off = 1; off < 512; off <<= 1) {
    int x = s[t];
    int y = (t >= off) ? s[t - off] : 0;
    __syncthreads();
    s[t] = x + y;
    __syncthreads();
  }
  if (i < ns) out[i] = s[t] - v;  // exclusive
  if (t == 511) bsum[blockIdx.y * 512 + blockIdx.x] = s[511];
}

__global__ void scan_bsums3(int* __restrict__ bsum, int B1, int B2, int B3) {
  int rel = blockIdx.x;
  int B = rel == 0 ? B1 : (rel == 1 ? B2 : B3);
  int* bs = bsum + rel * 512;
  __shared__ int s[512];
  int t = threadIdx.x;
  int v = (t < B) ? bs[t] : 0;
  s[t] = v;
  __syncthreads();
  for (int off = 1; off < 512; off <<= 1) {
    int x = s[t];
    int y = (t >= off) ? s[t - off] : 0;
    __syncthreads();
    s[t] = x + y;
    __syncthreads();
  }
  if (t < B) bs[t] = s[t] - v;  // exclusive
}

__global__ void addoff3(int* __restrict__ o1, int* __restrict__ p1, int ns1,
                        int* __restrict__ o2, int* __restrict__ p2, int ns2,
                        int* __restrict__ o3, int* __restrict__ p3, int ns3,
                        const int* __restrict__ bsum) {
  int* o; int* p; int ns;
  switch (blockIdx.y) {
    case 0: o = o1; p = p1; ns = ns1; break;
    case 1: o = o2; p = p2; ns = ns2; break;
    default: o = o3; p = p3; ns = ns3; break;
  }
  int i = blockIdx.x * 512 + threadIdx.x;
  if (i < ns) {
    int v = o[i] + bsum[blockIdx.y * 512 + blockIdx.x];
    o[i] = v;
    p[i] = v;
  }
}

__global__ void bucket3(
    const int* __restrict__ d1, const int* __restrict__ s1in,
    const float* __restrict__ w1in, int E1, int* __restrict__ p1,
    int* __restrict__ s1, float* __restrict__ w1,
    const int* __restrict__ d2, const int* __restrict__ s2in, int E2,
    int* __restrict__ p2, int* __restrict__ s2,
    const int* __restrict__ d3, const int* __restrict__ s3in, int E3,
    int* __restrict__ p3, int* __restrict__ s3) {
  int i = blockIdx.x * blockDim.x + threadIdx.x;
  int stride = gridDim.x * blockDim.x;
  int tot = E1 + E2 + E3;
  for (; i < tot; i += stride) {
    if (i < E1) {
      int p = atomicAdd(&p1[d1[i]], 1);
      s1[p] = s1in[i];
      w1[p] = w1in[i];
    } else if (i < E1 + E2) {
      int k = i - E1;
      int p = atomicAdd(&p2[d2[k]], 1);
      s2[p] = s2in[k];
    } else {
      int k = i - E1 - E2;
      int p = atomicAdd(&p3[d3[k]], 1);
      s3[p] = s3in[k];
    }
  }
}

// ------------- fused gather-accumulate + ELU (1 wave per dst row) -------------
template <bool WEIGHTED>
__device__ __forceinline__ void gather_acc(float4& v, const unsigned short* __restrict__ msg,
                                           const int* __restrict__ srcs,
                                           const float* __restrict__ wgts,
                                           int b, int e, int lane) {
  int j = b;
  for (; j + 4 <= e; j += 4) {
    int sa = srcs[j], sb = srcs[j + 1], sc = srcs[j + 2], sd = srcs[j + 3];
    float wa = 1.f, wb = 1.f, wc = 1.f, wd = 1.f;
    if (WEIGHTED) { wa = wgts[j]; wb = wgts[j + 1]; wc = wgts[j + 2]; wd = wgts[j + 3]; }
    ushort4 ma = *(const ushort4*)(msg + ((size_t)sa << 8) + lane * 4);
    ushort4 mb = *(const ushort4*)(msg + ((size_t)sb << 8) + lane * 4);
    ushort4 mc = *(const ushort4*)(msg + ((size_t)sc << 8) + lane * 4);
    ushort4 md = *(const ushort4*)(msg + ((size_t)sd << 8) + lane * 4);
    v.x += wa * b2f(ma.x) + wb * b2f(mb.x) + wc * b2f(mc.x) + wd * b2f(md.x);
    v.y += wa * b2f(ma.y) + wb * b2f(mb.y) + wc * b2f(mc.y) + wd * b2f(md.y);
    v.z += wa * b2f(ma.z) + wb * b2f(mb.z) + wc * b2f(mc.z) + wd * b2f(md.z);
    v.w += wa * b2f(ma.w) + wb * b2f(mb.w) + wc * b2f(mc.w) + wd * b2f(md.w);
  }
  for (; j < e; ++j) {
    int s = srcs[j];
    float w = WEIGHTED ? wgts[j] : 1.f;
    ushort4 m = *(const ushort4*)(msg + ((size_t)s << 8) + lane * 4);
    v.x += w * b2f(m.x); v.y += w * b2f(m.y);
    v.z += w * b2f(m.z); v.w += w * b2f(m.w);
  }
}

__global__ void accum_fused(
    float* __restrict__ io_p, int Np, float* __restrict__ io_a, int Na,
    const unsigned short* __restrict__ msg1, const int* __restrict__ off1,
    const int* __restrict__ s1, const float* __restrict__ w1,
    const unsigned short* __restrict__ msg2, const int* __restrict__ off2,
    const int* __restrict__ s2,
    const unsigned short* __restrict__ msg3, const int* __restrict__ off3,
    const int* __restrict__ s3) {
  int gw = (blockIdx.x * blockDim.x + threadIdx.x) >> 6;
  int lane = threadIdx.x & 63;
  float* rp;
  float4 v;
  if (gw < Np) {
    rp = io_p + (size_t)gw * 256 + lane * 4;
    v = *(float4*)rp;
    int j1 = off1[gw], e1 = off1[gw + 1];
    int j2 = off2[gw], e2 = off2[gw + 1];
    // merged main loop: 2 cites + 2 writes gathers in flight together
    while (j1 + 2 <= e1 && j2 + 2 <= e2) {
      int sa = s1[j1], sb = s1[j1 + 1];
      float wa = w1[j1], wb = w1[j1 + 1];
      int sc = s2[j2], sd = s2[j2 + 1];
      ushort4 ma = *(const ushort4*)(msg1 + ((size_t)sa << 8) + lane * 4);
      ushort4 mb = *(const ushort4*)(msg1 + ((size_t)sb << 8) + lane * 4);
      ushort4 mc = *(const ushort4*)(msg2 + ((size_t)sc << 8) + lane * 4);
      ushort4 md = *(const ushort4*)(msg2 + ((size_t)sd << 8) + lane * 4);
      v.x += wa * b2f(ma.x) + wb * b2f(mb.x) + b2f(mc.x) + b2f(md.x);
      v.y += wa * b2f(ma.y) + wb * b2f(mb.y) + b2f(mc.y) + b2f(md.y);
      v.z += wa * b2f(ma.z) + wb * b2f(mb.z) + b2f(mc.z) + b2f(md.z);
      v.w += wa * b2f(ma.w) + wb * b2f(mb.w) + b2f(mc.w) + b2f(md.w);
      j1 += 2; j2 += 2;
    }
    gather_acc<true>(v, msg1, s1, w1, j1, e1, lane);
    gather_acc<false>(v, msg2, s2, nullptr, j2, e2, lane);
  } else if (gw < Np + Na) {
    int r = gw - Np;
    rp = io_a + (size_t)r * 256 + lane * 4;
    v = *(float4*)rp;
    gather_acc<false>(v, msg3, s3, nullptr, off3[r], off3[r + 1], lane);
  } else {
    return;
  }
  float4 o;
  o.x = v.x > 0.f ? v.x : expf(v.x) - 1.f;
  o.y = v.y > 0.f ? v.y : expf(v.y) - 1.f;
  o.z = v.z > 0.f ? v.z : expf(v.z) - 1.f;
  o.w = v.w > 0.f ? v.w : expf(v.w) - 1.f;
  *(float4*)rp = o;
}

extern "C" void kernel_launch(void* const* d_in, const int* in_sizes, int n_in,
                              void* d_out, int out_size, void* d_ws, size_t ws_size,
                              hipStream_t stream) {
  const float* x_p = (const float*)d_in[0];
  const float* x_a = (const float*)d_in[1];
  const int* c_src = (const int*)d_in[2];
  const int* c_dst = (const int*)d_in[3];
  const float* c_w = (const float*)d_in[4];
  const int* w_src = (const int*)d_in[5];
  const int* w_dst = (const int*)d_in[6];
  const int* wr_src = (const int*)d_in[7];
  const int* wr_dst = (const int*)d_in[8];
  const float* W_sp = (const float*)d_in[9];
  const float* b_sp = (const float*)d_in[10];
  const float* W_sa = (const float*)d_in[11];
  const float* b_sa = (const float*)d_in[12];
  const float* W_c  = (const float*)d_in[13];
  const float* b_c  = (const float*)d_in[14];
  const float* W_w  = (const float*)d_in[15];
  const float* b_w  = (const float*)d_in[16];
  const float* W_wr = (const float*)d_in[17];
  const float* b_wr = (const float*)d_in[18];

  const int Mp = in_sizes[0] / 256;
  const int Ma = in_sizes[1] / 256;
  const int Ec = in_sizes[2], Ew = in_sizes[5], Ewr = in_sizes[7];

  // ---- workspace bump allocator (256B aligned); total ~187 MB ----
  size_t wo = 0;
  auto alloc = [&](size_t bytes) -> void* {
    void* p = (char*)d_ws + wo;
    wo += (bytes + 255) & ~(size_t)255;
    return p;
  };
  unsigned short* msg_c  = (unsigned short*)alloc((size_t)Mp * 512);
  unsigned short* msg_w  = (unsigned short*)alloc((size_t)Ma * 512);
  unsigned short* msg_wr = (unsigned short*)alloc((size_t)Mp * 512);
  unsigned short* Axp    = (unsigned short*)alloc((size_t)Mp * 512);  // bf16 x_p
  unsigned short* WT_sp = (unsigned short*)alloc(131072);
  unsigned short* WT_sa = (unsigned short*)alloc(131072);
  unsigned short* WT_c  = (unsigned short*)alloc(131072);
  unsigned short* WT_w  = (unsigned short*)alloc(131072);
  unsigned short* WT_wr = (unsigned short*)alloc(131072);
  int* cnt_c  = (int*)alloc((size_t)((Mp + 1) + (Mp + 1) + (Ma + 1)) * 4);
  int* cnt_w  = cnt_c + (Mp + 1);
  int* cnt_wr = cnt_w + (Mp + 1);
  size_t cnt_bytes = (size_t)((Mp + 1) + (Mp + 1) + (Ma + 1)) * 4;
  int* off_c  = (int*)alloc((size_t)(Mp + 1) * 4);
  int* pos_c  = (int*)alloc((size_t)(Mp + 1) * 4);
  int* off_w  = (int*)alloc((size_t)(Mp + 1) * 4);
  int* pos_w  = (int*)alloc((size_t)(Mp + 1) * 4);
  int* off_wr = (int*)alloc((size_t)(Ma + 1) * 4);
  int* pos_wr = (int*)alloc((size_t)(Ma + 1) * 4);
  int* srcs_c  = (int*)alloc((size_t)Ec * 4);
  float* wgts_c = (float*)alloc((size_t)Ec * 4);
  int* srcs_w  = (int*)alloc((size_t)Ew * 4);
  int* srcs_wr = (int*)alloc((size_t)Ewr * 4);
  int* bsum = (int*)alloc(3 * 512 * 4);

  float* out_p = (float*)d_out;
  float* out_a = (float*)d_out + (size_t)Mp * 256;

  // ---- prep: x_p -> bf16, weight transposes ----
  cvt_bf16<<<2048, 256, 0, stream>>>((const float4*)x_p, (ushort4*)Axp, Mp * 64);
  {
    dim3 g(64, 5);
    transpose_cast5<<<g, 256, 0, stream>>>(W_sp, W_sa, W_c, W_w, W_wr,
                                           WT_sp, WT_sa, WT_c, WT_w, WT_wr);
  }

  // ---- CSR build (6 dispatches) ----
  const int ns1 = Mp + 1, ns2 = Mp + 1, ns3 = Ma + 1;
  const int B1 = (ns1 + 511) / 512, B2 = (ns2 + 511) / 512, B3 = (ns3 + 511) / 512;
  const int Bmax = B1 > B2 ? (B1 > B3 ? B1 : B3) : (B2 > B3 ? B2 : B3);
  hipMemsetAsync(cnt_c, 0, cnt_bytes, stream);
  hist3<<<256, 256, 0, stream>>>(c_dst, Ec, cnt_c, w_dst, Ew, cnt_w, wr_dst, Ewr, cnt_wr);
  {
    dim3 g(Bmax, 3);
    scan512_3<<<g, 512, 0, stream>>>(cnt_c, off_c, ns1, cnt_w, off_w, ns2,
                                     cnt_wr, off_wr, ns3, bsum);
    scan_bsums3<<<3, 512, 0, stream>>>(bsum, B1, B2, B3);
    addoff3<<<g, 512, 0, stream>>>(off_c, pos_c, ns1, off_w, pos_w, ns2,
                                   off_wr, pos_wr, ns3, bsum);
  }
  bucket3<<<256, 256, 0, stream>>>(c_dst, c_src, c_w, Ec, pos_c, srcs_c, wgts_c,
                                   w_dst, w_src, Ew, pos_w, srcs_w,
                                   wr_dst, wr_src, Ewr, pos_wr, srcs_wr);

  // ---- fused GEMMs (XCD-swizzled 1-D grids) ----
  const int nsp = (Mp + 127) / 128, nsa = (Ma + 127) / 128;
  gemm_multi<3, true><<<nsp * 4, 256, 0, stream>>>(
      Axp, WT_sp, WT_c, WT_wr, b_sp, b_c, b_wr, out_p, msg_c, msg_wr, Mp, nsp);
  gemm_multi<2, false><<<nsa * 4, 256, 0, stream>>>(
      x_a, WT_sa, WT_w, nullptr, b_sa, b_w, nullptr, out_a, msg_w, nullptr, Ma, nsa);

  // ---- fused gather-accumulate + ELU (1 wave per row) ----
  int totalWaves = Mp + Ma;
  accum_fused<<<(totalWaves + 3) / 4, 256, 0, stream>>>(
      out_p, Mp, out_a, Ma,
      msg_c, off_c, srcs_c, wgts_c,
      msg_w, off_w, srcs_w,
      msg_wr, off_wr, srcs_wr);
}